// Round 5
// baseline (42.133 us; speedup 1.0000x reference)
//
#include <hip/hip_runtime.h>
#include <hip/hip_bf16.h>
#include <math.h>
#include <stdint.h>

#define BV 4
#define NV 1024
#define IND 128
#define OUTD 128
#define NH 8
#define DD 16
#define LOG2E 1.4426950408889634f

typedef __attribute__((ext_vector_type(8))) short bf16x8;
typedef __attribute__((ext_vector_type(4))) float f32x4;

__device__ __forceinline__ ushort bf16rne(float f) {
    uint32_t u = __float_as_uint(f);
    u += 0x7fff + ((u >> 16) & 1);
    return (ushort)(u >> 16);
}

// ---- kernel A: block-specialized {projection+transpose+dots | mask bits} ----
__global__ __launch_bounds__(256) void kA(
    const float* __restrict__ x, const float* __restrict__ adj,
    const float* __restrict__ W, const float* __restrict__ a,
    uint32_t* __restrict__ bits, ushort* __restrict__ xhi, ushort* __restrict__ xlo,
    float* __restrict__ src, float* __restrict__ dst_t)
{
    const int pid = blockIdx.x;
    const int tid = threadIdx.x;

    if (pid >= 512) {
        // ---------------- mask bitwords (diagonal forced in) ----------------
        const int row = pid - 512;           // b*NV + i
        const int i = row & (NV - 1);
        const int wave = tid >> 6, lane = tid & 63;
        const float* arow = adj + (size_t)row * NV;
        #pragma unroll
        for (int r = 0; r < 4; ++r) {
            const int j = (r * 4 + wave) * 64 + lane;
            const bool m = (arow[j] > 0.f) || (j == i);
            const unsigned long long bal = __ballot(m);
            if (lane == 0) {
                bits[(size_t)row * 32 + (r * 4 + wave) * 2]     = (uint32_t)bal;
                bits[(size_t)row * 32 + (r * 4 + wave) * 2 + 1] = (uint32_t)(bal >> 32);
            }
        }
        return;
    }

    // ------------- projection: 64-row x 16-d tile per block ------------------
    const int jt = pid & 15, bh = pid >> 4;  // bh = b*8+h
    const int b = bh >> 3, h = bh & 7;
    const int j0 = jt * 64;
    const int jl = tid >> 2, dq = tid & 3;   // 4 threads per row, 4 d each
    const int gj = b * NV + j0 + jl;

    float acc0 = 0.f, acc1 = 0.f, acc2 = 0.f, acc3 = 0.f;
    const float* xrow = x + (size_t)gj * IND;
    const float* wcol = W + h * DD + dq * 4;

    #pragma unroll
    for (int kc = 0; kc < IND; kc += 32) {
        float4 xr[8];
        #pragma unroll
        for (int u = 0; u < 8; ++u)
            xr[u] = *(const float4*)&xrow[kc + u * 4];
        #pragma unroll
        for (int u = 0; u < 8; ++u) {
            #pragma unroll
            for (int v = 0; v < 4; ++v) {
                const float xs = ((const float*)&xr[u])[v];
                const float4 w = *(const float4*)&wcol[(size_t)(kc + u * 4 + v) * OUTD];
                acc0 = fmaf(xs, w.x, acc0);
                acc1 = fmaf(xs, w.y, acc1);
                acc2 = fmaf(xs, w.z, acc2);
                acc3 = fmaf(xs, w.w, acc3);
            }
        }
    }

    // src/dst per-head dots (4-lane partial -> combine), pre-scaled by log2e
    {
        const int d0 = dq * 4;
        float s = acc0 * a[d0] + acc1 * a[d0 + 1] + acc2 * a[d0 + 2] + acc3 * a[d0 + 3];
        float t = acc0 * a[DD + d0] + acc1 * a[DD + d0 + 1] + acc2 * a[DD + d0 + 2] + acc3 * a[DD + d0 + 3];
        s += __shfl_xor(s, 1); s += __shfl_xor(s, 2);
        t += __shfl_xor(t, 1); t += __shfl_xor(t, 2);
        if (dq == 0) {
            src[(size_t)gj * NH + h] = s * LOG2E;
            dst_t[(size_t)bh * NV + j0 + jl] = t * LOG2E;
        }
    }

    // bf16 hi/lo split, transpose to [d][j] via small LDS tile
    __shared__ ushort thi[16][80];
    __shared__ ushort tlo[16][80];
    {
        const float av[4] = {acc0, acc1, acc2, acc3};
        #pragma unroll
        for (int i2 = 0; i2 < 4; ++i2) {
            const ushort hb = bf16rne(av[i2]);
            const float fh = __uint_as_float(((uint32_t)hb) << 16);
            const ushort lb = bf16rne(av[i2] - fh);
            thi[dq * 4 + i2][jl] = hb;
            tlo[dq * 4 + i2][jl] = lb;
        }
    }
    __syncthreads();
    if (tid < 128) {
        const int d = tid >> 3, jo = tid & 7;
        const uint4 vh = *(const uint4*)&thi[d][jo * 8];
        const uint4 vl = *(const uint4*)&tlo[d][jo * 8];
        const size_t base = ((size_t)(bh * 16 + d)) * NV + j0 + jo * 8;
        *(uint4*)&xhi[base] = vh;
        *(uint4*)&xlo[base] = vl;
    }
}

// ------------- kernel B: flash-style masked softmax + MFMA (j-split) --------
__global__ __launch_bounds__(512, 4) void kB(
    const uint32_t* __restrict__ bits, const ushort* __restrict__ xhi,
    const ushort* __restrict__ xlo, const float* __restrict__ dst_t,
    const float* __restrict__ src, float* __restrict__ out)
{
    // grid 512; blocks on one XCD share (b,h)
    const int bid = blockIdx.x;
    const int xcd = bid & 7, sl = bid >> 3;  // sl 0..63
    const int bh = xcd * 4 + (sl >> 4);      // 0..31
    const int it = sl & 15;
    const int b = bh >> 3, h = bh & 7;
    const int i0 = it * 64;

    const int tid = threadIdx.x;
    const int wv = tid >> 6, lane = tid & 63;
    const int g = lane >> 4, r16 = lane & 15;
    const int rg = wv & 3;                   // row group (16 rows)
    const int jh = wv >> 2;                  // j half (512 each)

    __shared__ ushort ahi[16 * 1032];        // [d][j] padded
    __shared__ ushort alo[16 * 1032];
    __shared__ float dstl[NV];
    __shared__ uint32_t bl[64 * 33];         // mask bits; aliased as red buf later
    __shared__ float mxx[2][64];

    // ---- stage ----
    const uint4* ghi = (const uint4*)(xhi + (size_t)bh * 16 * NV);
    const uint4* glo = (const uint4*)(xlo + (size_t)bh * 16 * NV);
    #pragma unroll
    for (int k = 0; k < 4; ++k) {
        const int idx = tid + k * 512;       // 2048 uint4
        const int d = idx >> 7, jo = idx & 127;
        *(uint4*)&ahi[d * 1032 + jo * 8] = ghi[idx];
        *(uint4*)&alo[d * 1032 + jo * 8] = glo[idx];
    }
    if (tid < 256) {
        const float4* gd = (const float4*)(dst_t + (size_t)bh * NV);
        *(float4*)&dstl[tid * 4] = gd[tid];
    }
    #pragma unroll
    for (int k = 0; k < 4; ++k) {
        const int idx = tid + k * 512;       // 2048 words
        const int rr = idx >> 5, w = idx & 31;
        bl[rr * 33 + w] = bits[((size_t)(b * NV) + i0 + rr) * 32 + w];
    }
    const int myrow = rg * 16 + r16;
    const float srcv = src[((size_t)(b * NV) + i0 + myrow) * NH + h];
    __syncthreads();

    // ---- prepass: masked max of dst over this wave's j-half ----
    float dmax = -INFINITY;
    #pragma unroll 4
    for (int st = 0; st < 16; ++st) {
        const int jj = jh * 512 + g * 128 + st * 8;
        const uint32_t word = bl[myrow * 33 + (jj >> 5)];
        const uint32_t bb = (word >> (jj & 31)) & 0xffu;
        const float4 v0 = *(const float4*)&dstl[jj];
        const float4 v1 = *(const float4*)&dstl[jj + 4];
        if (bb & 0x01u) dmax = fmaxf(dmax, v0.x);
        if (bb & 0x02u) dmax = fmaxf(dmax, v0.y);
        if (bb & 0x04u) dmax = fmaxf(dmax, v0.z);
        if (bb & 0x08u) dmax = fmaxf(dmax, v0.w);
        if (bb & 0x10u) dmax = fmaxf(dmax, v1.x);
        if (bb & 0x20u) dmax = fmaxf(dmax, v1.y);
        if (bb & 0x40u) dmax = fmaxf(dmax, v1.z);
        if (bb & 0x80u) dmax = fmaxf(dmax, v1.w);
    }
    dmax = fmaxf(dmax, __shfl_xor(dmax, 16));
    dmax = fmaxf(dmax, __shfl_xor(dmax, 32));
    if (g == 0) mxx[jh][myrow] = dmax;       // one lane per (row, half)
    __syncthreads();
    dmax = fmaxf(mxx[0][myrow], mxx[1][myrow]);
    const float S = srcv + dmax;
    const float mx = fmaxf(S, 0.2f * S);     // same op chain as per-element

    // ---- main K-loop over this wave's j-half ----
    f32x4 acc = {0.f, 0.f, 0.f, 0.f};
    float den = 0.f;
    const int shift = g * 8;
    #pragma unroll 2
    for (int s = 0; s < 16; ++s) {
        const int sw = jh * 16 + s;          // bit-word index
        const int js = sw * 32 + shift;
        const uint32_t bb = (bl[myrow * 33 + sw] >> shift) & 0xffu;
        const float4 d0 = *(const float4*)&dstl[js];
        const float4 d1 = *(const float4*)&dstl[js + 4];
        const float dv[8] = {d0.x, d0.y, d0.z, d0.w, d1.x, d1.y, d1.z, d1.w};
        union { __hip_bfloat162 h2[4]; bf16x8 v; } af;
        #pragma unroll
        for (int p = 0; p < 4; ++p) {
            const float s0 = srcv + dv[2 * p];
            const float s1 = srcv + dv[2 * p + 1];
            const float e0 = fmaxf(s0, 0.2f * s0);
            const float e1 = fmaxf(s1, 0.2f * s1);
            const float a0 = (bb & (1u << (2 * p))) ? (e0 - mx) : 0.0f;
            const float a1 = (bb & (1u << (2 * p + 1))) ? (e1 - mx) : 0.0f;
            const float w0 = exp2f(a0);
            const float w1 = exp2f(a1);
            den += w0 + w1;
            af.h2[p] = __float22bfloat162_rn(make_float2(w0, w1));
        }
        const bf16x8 vh = *(const bf16x8*)&ahi[r16 * 1032 + js];
        const bf16x8 vl = *(const bf16x8*)&alo[r16 * 1032 + js];
        acc = __builtin_amdgcn_mfma_f32_16x16x32_bf16(af.v, vh, acc, 0, 0, 0);
        acc = __builtin_amdgcn_mfma_f32_16x16x32_bf16(af.v, vl, acc, 0, 0, 0);
    }
    __syncthreads();                          // bl dead from here; alias as red

    float* red_acc = (float*)bl;              // 4 waves * 64 lanes * 4 = 4 KB
    float* red_den = (float*)bl + 1024;       // 4 waves * 64 lanes   = 1 KB
    if (jh == 1) {
        *(float4*)&red_acc[(rg * 64 + lane) * 4] = *(float4*)&acc;
        red_den[rg * 64 + lane] = den;
    }
    __syncthreads();

    if (jh == 0) {
        const float4 oa = *(const float4*)&red_acc[(rg * 64 + lane) * 4];
        acc[0] += oa.x; acc[1] += oa.y; acc[2] += oa.z; acc[3] += oa.w;
        den += red_den[rg * 64 + lane];
        den += __shfl_xor(den, 16);
        den += __shfl_xor(den, 32);           // full-row den at matching r16
        #pragma unroll
        for (int q = 0; q < 4; ++q) {
            const int orow = g * 4 + q;       // C row for this lane
            const float dq = __shfl(den, orow);
            float rv = acc[q] / dq;
            rv = fmaxf(rv, 0.f);
            out[((size_t)(b * NV) + i0 + rg * 16 + orow) * OUTD + h * 16 + r16] = rv;
        }
    }
}

extern "C" void kernel_launch(void* const* d_in, const int* in_sizes, int n_in,
                              void* d_out, int out_size, void* d_ws, size_t ws_size,
                              hipStream_t stream)
{
    const float* x   = (const float*)d_in[0];
    const float* adj = (const float*)d_in[1];
    const float* W   = (const float*)d_in[2];
    const float* a   = (const float*)d_in[3];
    float* out = (float*)d_out;

    char* ws = (char*)d_ws;
    ushort* xhi    = (ushort*)ws;                                  // 1 MB
    ushort* xlo    = (ushort*)(ws + 1024 * 1024);                  // 1 MB
    float* dst_t   = (float*)(ws + 2 * 1024 * 1024);               // 128 KB
    float* src     = (float*)(ws + 2 * 1024 * 1024 + 128 * 1024);  // 128 KB
    uint32_t* bits = (uint32_t*)(ws + 2 * 1024 * 1024 + 256 * 1024);   // 512 KB

    kA<<<512 + BV * NV, 256, 0, stream>>>(x, adj, W, a, bits, xhi, xlo, src, dst_t);
    kB<<<512, 512, 0, stream>>>(bits, xhi, xlo, dst_t, src, out);
}

// Round 6
// 41.166 us; speedup vs baseline: 1.0235x; 1.0235x over previous
//
#include <hip/hip_runtime.h>
#include <hip/hip_bf16.h>
#include <math.h>
#include <stdint.h>

#define BV 4
#define NV 1024
#define IND 128
#define OUTD 128
#define NH 8
#define DD 16
#define LOG2E 1.4426950408889634f

typedef __attribute__((ext_vector_type(8))) short bf16x8;
typedef __attribute__((ext_vector_type(4))) float f32x4;

__device__ __forceinline__ ushort bf16rne(float f) {
    uint32_t u = __float_as_uint(f);
    u += 0x7fff + ((u >> 16) & 1);
    return (ushort)(u >> 16);
}

// ---- kernel A: block-specialized {projection+transpose+dots | mask bits} ----
__global__ __launch_bounds__(256) void kA(
    const float* __restrict__ x, const float* __restrict__ adj,
    const float* __restrict__ W, const float* __restrict__ a,
    uint32_t* __restrict__ bits, ushort* __restrict__ xhi,
    float* __restrict__ src, float* __restrict__ dst_t)
{
    const int pid = blockIdx.x;
    const int tid = threadIdx.x;

    if (pid >= 512) {
        // ---------------- mask bitwords (diagonal forced in) ----------------
        const int row = pid - 512;           // b*NV + i
        const int i = row & (NV - 1);
        const int wave = tid >> 6, lane = tid & 63;
        const float* arow = adj + (size_t)row * NV;
        #pragma unroll
        for (int r = 0; r < 4; ++r) {
            const int j = (r * 4 + wave) * 64 + lane;
            const bool m = (arow[j] > 0.f) || (j == i);
            const unsigned long long bal = __ballot(m);
            if (lane == 0) {
                bits[(size_t)row * 32 + (r * 4 + wave) * 2]     = (uint32_t)bal;
                bits[(size_t)row * 32 + (r * 4 + wave) * 2 + 1] = (uint32_t)(bal >> 32);
            }
        }
        return;
    }

    // ------------- projection: 64-row x 16-d tile per block ------------------
    const int jt = pid & 15, bh = pid >> 4;  // bh = b*8+h
    const int b = bh >> 3, h = bh & 7;
    const int j0 = jt * 64;
    const int jl = tid >> 2, dq = tid & 3;   // 4 threads per row, 4 d each
    const int gj = b * NV + j0 + jl;

    float acc0 = 0.f, acc1 = 0.f, acc2 = 0.f, acc3 = 0.f;
    const float* xrow = x + (size_t)gj * IND;
    const float* wcol = W + h * DD + dq * 4;

    #pragma unroll
    for (int kc = 0; kc < IND; kc += 32) {
        float4 xr[8];
        #pragma unroll
        for (int u = 0; u < 8; ++u)
            xr[u] = *(const float4*)&xrow[kc + u * 4];
        #pragma unroll
        for (int u = 0; u < 8; ++u) {
            #pragma unroll
            for (int v = 0; v < 4; ++v) {
                const float xs = ((const float*)&xr[u])[v];
                const float4 w = *(const float4*)&wcol[(size_t)(kc + u * 4 + v) * OUTD];
                acc0 = fmaf(xs, w.x, acc0);
                acc1 = fmaf(xs, w.y, acc1);
                acc2 = fmaf(xs, w.z, acc2);
                acc3 = fmaf(xs, w.w, acc3);
            }
        }
    }

    // src/dst per-head dots (4-lane partial -> combine), pre-scaled by log2e
    {
        const int d0 = dq * 4;
        float s = acc0 * a[d0] + acc1 * a[d0 + 1] + acc2 * a[d0 + 2] + acc3 * a[d0 + 3];
        float t = acc0 * a[DD + d0] + acc1 * a[DD + d0 + 1] + acc2 * a[DD + d0 + 2] + acc3 * a[DD + d0 + 3];
        s += __shfl_xor(s, 1); s += __shfl_xor(s, 2);
        t += __shfl_xor(t, 1); t += __shfl_xor(t, 2);
        if (dq == 0) {
            src[(size_t)gj * NH + h] = s * LOG2E;
            dst_t[(size_t)bh * NV + j0 + jl] = t * LOG2E;
        }
    }

    // bf16 round, transpose to [d][j] via small LDS tile
    __shared__ ushort thi[16][80];
    {
        const float av[4] = {acc0, acc1, acc2, acc3};
        #pragma unroll
        for (int i2 = 0; i2 < 4; ++i2)
            thi[dq * 4 + i2][jl] = bf16rne(av[i2]);
    }
    __syncthreads();
    if (tid < 128) {
        const int d = tid >> 3, jo = tid & 7;
        const uint4 vh = *(const uint4*)&thi[d][jo * 8];
        const size_t base = ((size_t)(bh * 16 + d)) * NV + j0 + jo * 8;
        *(uint4*)&xhi[base] = vh;
    }
}

// ------------- kernel B: flash-style masked softmax + MFMA (j-split) --------
__global__ __launch_bounds__(512, 6) void kB(
    const uint32_t* __restrict__ bits, const ushort* __restrict__ xhi,
    const float* __restrict__ dst_t, const float* __restrict__ src,
    float* __restrict__ out)
{
    // grid 512; blocks on one XCD share (b,h)
    const int bid = blockIdx.x;
    const int xcd = bid & 7, sl = bid >> 3;  // sl 0..63
    const int bh = xcd * 4 + (sl >> 4);      // 0..31
    const int it = sl & 15;
    const int b = bh >> 3, h = bh & 7;
    const int i0 = it * 64;

    const int tid = threadIdx.x;
    const int wv = tid >> 6, lane = tid & 63;
    const int g = lane >> 4, r16 = lane & 15;
    const int rg = wv & 3;                   // row group (16 rows)
    const int jh = wv >> 2;                  // j half (512 each)

    __shared__ ushort ahi[16 * 1032];        // [d][j] padded (33 KB)
    __shared__ float dstl[NV];               // 4 KB
    __shared__ uint32_t bl[64 * 33];         // mask bits (8.25 KB); aliased later
    __shared__ float mxx[2][64];

    // ---- stage ----
    const uint4* ghi = (const uint4*)(xhi + (size_t)bh * 16 * NV);
    #pragma unroll
    for (int k = 0; k < 4; ++k) {
        const int idx = tid + k * 512;       // 2048 uint4
        const int d = idx >> 7, jo = idx & 127;
        *(uint4*)&ahi[d * 1032 + jo * 8] = ghi[idx];
    }
    if (tid < 256) {
        const float4* gd = (const float4*)(dst_t + (size_t)bh * NV);
        *(float4*)&dstl[tid * 4] = gd[tid];
    }
    #pragma unroll
    for (int k = 0; k < 4; ++k) {
        const int idx = tid + k * 512;       // 2048 words
        const int rr = idx >> 5, w = idx & 31;
        bl[rr * 33 + w] = bits[((size_t)(b * NV) + i0 + rr) * 32 + w];
    }
    const int myrow = rg * 16 + r16;
    const float srcv = src[((size_t)(b * NV) + i0 + myrow) * NH + h];
    __syncthreads();

    // ---- prepass: masked max of dst over this wave's j-half (scalar reads) --
    float dmax = -INFINITY;
    #pragma unroll 2
    for (int st = 0; st < 16; ++st) {
        const int jj = jh * 512 + g * 128 + st * 8;
        const uint32_t word = bl[myrow * 33 + (jj >> 5)];
        const uint32_t bb = (word >> (jj & 31)) & 0xffu;
        #pragma unroll
        for (int t = 0; t < 8; ++t) {
            const float dv = dstl[jj + t];
            dmax = (bb & (1u << t)) ? fmaxf(dmax, dv) : dmax;
        }
    }
    dmax = fmaxf(dmax, __shfl_xor(dmax, 16));
    dmax = fmaxf(dmax, __shfl_xor(dmax, 32));
    if (g == 0) mxx[jh][myrow] = dmax;       // one lane per (row, half)
    __syncthreads();
    dmax = fmaxf(mxx[0][myrow], mxx[1][myrow]);
    const float S = srcv + dmax;
    const float mx = fmaxf(S, 0.2f * S);     // same op chain as per-element

    // ---- main K-loop over this wave's j-half (scalar dstl reads) ----
    f32x4 acc = {0.f, 0.f, 0.f, 0.f};
    float den = 0.f;
    const int shift = g * 8;
    #pragma unroll 2
    for (int s = 0; s < 16; ++s) {
        const int sw = jh * 16 + s;          // bit-word index
        const int js = sw * 32 + shift;
        const uint32_t bb = (bl[myrow * 33 + sw] >> shift) & 0xffu;
        union { __hip_bfloat162 h2[4]; bf16x8 v; } af;
        #pragma unroll
        for (int p = 0; p < 4; ++p) {
            const float dv0 = dstl[js + 2 * p];
            const float dv1 = dstl[js + 2 * p + 1];
            const float s0 = srcv + dv0;
            const float s1 = srcv + dv1;
            const float e0 = fmaxf(s0, 0.2f * s0);
            const float e1 = fmaxf(s1, 0.2f * s1);
            const float a0 = (bb & (1u << (2 * p))) ? (e0 - mx) : 0.0f;
            const float a1 = (bb & (1u << (2 * p + 1))) ? (e1 - mx) : 0.0f;
            const float w0 = exp2f(a0);
            const float w1 = exp2f(a1);
            den += w0 + w1;
            af.h2[p] = __float22bfloat162_rn(make_float2(w0, w1));
        }
        const bf16x8 vh = *(const bf16x8*)&ahi[r16 * 1032 + js];
        acc = __builtin_amdgcn_mfma_f32_16x16x32_bf16(af.v, vh, acc, 0, 0, 0);
    }
    __syncthreads();                          // bl dead from here; alias as red

    float* red_acc = (float*)bl;              // 256 lanes * 4 = 4 KB
    float* red_den = (float*)bl + 1024;       // 256 floats    = 1 KB
    if (jh == 1) {
        *(float4*)&red_acc[(rg * 64 + lane) * 4] = *(float4*)&acc;
        red_den[rg * 64 + lane] = den;
    }
    __syncthreads();

    if (jh == 0) {
        const float4 oa = *(const float4*)&red_acc[(rg * 64 + lane) * 4];
        acc[0] += oa.x; acc[1] += oa.y; acc[2] += oa.z; acc[3] += oa.w;
        den += red_den[rg * 64 + lane];
        den += __shfl_xor(den, 16);
        den += __shfl_xor(den, 32);           // full-row den at matching r16
        #pragma unroll
        for (int q = 0; q < 4; ++q) {
            const int orow = g * 4 + q;       // C row for this lane
            const float dq = __shfl(den, orow);
            float rv = acc[q] / dq;
            rv = fmaxf(rv, 0.f);
            out[((size_t)(b * NV) + i0 + rg * 16 + orow) * OUTD + h * 16 + r16] = rv;
        }
    }
}

extern "C" void kernel_launch(void* const* d_in, const int* in_sizes, int n_in,
                              void* d_out, int out_size, void* d_ws, size_t ws_size,
                              hipStream_t stream)
{
    const float* x   = (const float*)d_in[0];
    const float* adj = (const float*)d_in[1];
    const float* W   = (const float*)d_in[2];
    const float* a   = (const float*)d_in[3];
    float* out = (float*)d_out;

    char* ws = (char*)d_ws;
    ushort* xhi    = (ushort*)ws;                                  // 1 MB
    float* dst_t   = (float*)(ws + 1024 * 1024);                   // 128 KB
    float* src     = (float*)(ws + 1024 * 1024 + 128 * 1024);      // 128 KB
    uint32_t* bits = (uint32_t*)(ws + 1024 * 1024 + 256 * 1024);   // 512 KB

    kA<<<512 + BV * NV, 256, 0, stream>>>(x, adj, W, a, bits, xhi, src, dst_t);
    kB<<<512, 512, 0, stream>>>(bits, xhi, dst_t, src, out);
}

// Round 7
// 37.848 us; speedup vs baseline: 1.1132x; 1.0877x over previous
//
#include <hip/hip_runtime.h>
#include <hip/hip_bf16.h>
#include <math.h>
#include <stdint.h>

#define BV 4
#define NV 1024
#define IND 128
#define OUTD 128
#define NH 8
#define DD 16
#define LOG2E 1.4426950408889634f

typedef __attribute__((ext_vector_type(8))) short bf16x8;
typedef __attribute__((ext_vector_type(4))) float f32x4;

__device__ __forceinline__ ushort bf16rne(float f) {
    uint32_t u = __float_as_uint(f);
    u += 0x7fff + ((u >> 16) & 1);
    return (ushort)(u >> 16);
}

// ---- kernel A: block-specialized {projection+transpose+dots | mask bits} ----
__global__ __launch_bounds__(256) void kA(
    const float* __restrict__ x, const float* __restrict__ adj,
    const float* __restrict__ W, const float* __restrict__ a,
    uint32_t* __restrict__ bits, ushort* __restrict__ xhi,
    float* __restrict__ src, float* __restrict__ dst_t)
{
    const int pid = blockIdx.x;
    const int tid = threadIdx.x;

    if (pid >= 512) {
        // ---------------- mask bitwords (diagonal forced in) ----------------
        const int row = pid - 512;           // b*NV + i
        const int i = row & (NV - 1);
        const int wave = tid >> 6, lane = tid & 63;
        const float* arow = adj + (size_t)row * NV;
        #pragma unroll
        for (int r = 0; r < 4; ++r) {
            const int j = (r * 4 + wave) * 64 + lane;
            const bool m = (arow[j] > 0.f) || (j == i);
            const unsigned long long bal = __ballot(m);
            if (lane == 0) {
                bits[(size_t)row * 32 + (r * 4 + wave) * 2]     = (uint32_t)bal;
                bits[(size_t)row * 32 + (r * 4 + wave) * 2 + 1] = (uint32_t)(bal >> 32);
            }
        }
        return;
    }

    // ------------- projection: 64-row x 16-d tile per block ------------------
    const int jt = pid & 15, bh = pid >> 4;  // bh = b*8+h
    const int b = bh >> 3, h = bh & 7;
    const int j0 = jt * 64;
    const int jl = tid >> 2, dq = tid & 3;   // 4 threads per row, 4 d each
    const int gj = b * NV + j0 + jl;

    float acc0 = 0.f, acc1 = 0.f, acc2 = 0.f, acc3 = 0.f;
    const float* xrow = x + (size_t)gj * IND;
    const float* wcol = W + h * DD + dq * 4;

    #pragma unroll
    for (int kc = 0; kc < IND; kc += 32) {
        float4 xr[8];
        #pragma unroll
        for (int u = 0; u < 8; ++u)
            xr[u] = *(const float4*)&xrow[kc + u * 4];
        #pragma unroll
        for (int u = 0; u < 8; ++u) {
            #pragma unroll
            for (int v = 0; v < 4; ++v) {
                const float xs = ((const float*)&xr[u])[v];
                const float4 w = *(const float4*)&wcol[(size_t)(kc + u * 4 + v) * OUTD];
                acc0 = fmaf(xs, w.x, acc0);
                acc1 = fmaf(xs, w.y, acc1);
                acc2 = fmaf(xs, w.z, acc2);
                acc3 = fmaf(xs, w.w, acc3);
            }
        }
    }

    // src/dst per-head dots (4-lane partial -> combine), pre-scaled by log2e
    {
        const int d0 = dq * 4;
        float s = acc0 * a[d0] + acc1 * a[d0 + 1] + acc2 * a[d0 + 2] + acc3 * a[d0 + 3];
        float t = acc0 * a[DD + d0] + acc1 * a[DD + d0 + 1] + acc2 * a[DD + d0 + 2] + acc3 * a[DD + d0 + 3];
        s += __shfl_xor(s, 1); s += __shfl_xor(s, 2);
        t += __shfl_xor(t, 1); t += __shfl_xor(t, 2);
        if (dq == 0) {
            src[(size_t)gj * NH + h] = s * LOG2E;
            dst_t[(size_t)bh * NV + j0 + jl] = t * LOG2E;
        }
    }

    // bf16 round, transpose to [d][j] via small LDS tile
    __shared__ ushort thi[16][80];
    {
        const float av[4] = {acc0, acc1, acc2, acc3};
        #pragma unroll
        for (int i2 = 0; i2 < 4; ++i2)
            thi[dq * 4 + i2][jl] = bf16rne(av[i2]);
    }
    __syncthreads();
    if (tid < 128) {
        const int d = tid >> 3, jo = tid & 7;
        const uint4 vh = *(const uint4*)&thi[d][jo * 8];
        const size_t base = ((size_t)(bh * 16 + d)) * NV + j0 + jo * 8;
        *(uint4*)&xhi[base] = vh;
    }
}

// --- kernel B: 16-row blocks, 4 j-quarter waves, regs-bits, B-from-global ---
__global__ __launch_bounds__(256, 4) void kB(
    const uint32_t* __restrict__ bits, const ushort* __restrict__ xhi,
    const float* __restrict__ dst_t, const float* __restrict__ src,
    float* __restrict__ out)
{
    // grid 2048; XCD-swizzle: blocks on one XCD share 4 bh slabs
    const int bid = blockIdx.x;
    const int xcd = bid & 7, t2 = (bid >> 3) & 3, it = bid >> 5;
    const int bh = xcd * 4 + t2;             // 0..31
    const int b = bh >> 3, h = bh & 7;
    const int i0 = it * 16;

    const int tid = threadIdx.x;
    const int jq = tid >> 6, lane = tid & 63;  // wave = j-quarter
    const int g = lane >> 4, r16 = lane & 15;

    __shared__ float dstl[NV];               // 4 KB
    __shared__ float mxr[4][16];
    __shared__ float red_acc[3][64][4];      // 3 KB
    __shared__ float red_den[3][64];

    // ---- stage dstl + per-lane globals ----
    {
        const float4* gd = (const float4*)(dst_t + (size_t)bh * NV);
        *(float4*)&dstl[tid * 4] = gd[tid];
    }
    const int grow = b * NV + i0 + r16;      // this lane's i-row
    const float srcv = src[(size_t)grow * NH + h];
    uint32_t blw[8];
    #pragma unroll
    for (int s = 0; s < 8; ++s)
        blw[s] = bits[(size_t)grow * 32 + jq * 8 + s];
    __syncthreads();

    // ---- prepass: masked max of dst over this wave's j-quarter ----
    float dmax = -INFINITY;
    #pragma unroll
    for (int s = 0; s < 8; ++s) {
        const int base = jq * 256 + s * 32 + g * 8;
        const uint32_t bb = (blw[s] >> (g * 8)) & 0xffu;
        #pragma unroll
        for (int t = 0; t < 8; ++t) {
            const float dv = dstl[base + t];
            dmax = (bb & (1u << t)) ? fmaxf(dmax, dv) : dmax;
        }
    }
    dmax = fmaxf(dmax, __shfl_xor(dmax, 16));
    dmax = fmaxf(dmax, __shfl_xor(dmax, 32));
    if (g == 0) mxr[jq][r16] = dmax;
    __syncthreads();
    dmax = fmaxf(fmaxf(mxr[0][r16], mxr[1][r16]), fmaxf(mxr[2][r16], mxr[3][r16]));
    const float S = srcv + dmax;
    const float mx = fmaxf(S, 0.2f * S);     // same op chain as per-element

    // ---- main loop: 8 iters over this wave's j-quarter ----
    f32x4 acc = {0.f, 0.f, 0.f, 0.f};
    float den = 0.f;
    const ushort* xrow = xhi + ((size_t)(bh * 16 + r16)) * NV;
    #pragma unroll
    for (int s = 0; s < 8; ++s) {
        const int base = jq * 256 + s * 32 + g * 8;
        const uint32_t bb = (blw[s] >> (g * 8)) & 0xffu;
        union { __hip_bfloat162 h2[4]; bf16x8 v; } af;
        #pragma unroll
        for (int p = 0; p < 4; ++p) {
            const float dv0 = dstl[base + 2 * p];
            const float dv1 = dstl[base + 2 * p + 1];
            const float s0 = srcv + dv0;
            const float s1 = srcv + dv1;
            const float e0 = fmaxf(s0, 0.2f * s0);
            const float e1 = fmaxf(s1, 0.2f * s1);
            const float a0 = (bb & (1u << (2 * p))) ? (e0 - mx) : 0.0f;
            const float a1 = (bb & (1u << (2 * p + 1))) ? (e1 - mx) : 0.0f;
            const float w0 = exp2f(a0);
            const float w1 = exp2f(a1);
            den += w0 + w1;
            af.h2[p] = __float22bfloat162_rn(make_float2(w0, w1));
        }
        const bf16x8 vh = *(const bf16x8*)&xrow[base];   // B-frag from L1/L2
        acc = __builtin_amdgcn_mfma_f32_16x16x32_bf16(af.v, vh, acc, 0, 0, 0);
    }

    // ---- epilogue: cross-quarter reduce + normalize + relu + store ----
    if (jq > 0) {
        *(float4*)&red_acc[jq - 1][lane][0] = *(float4*)&acc;
        red_den[jq - 1][lane] = den;
    }
    __syncthreads();
    if (jq == 0) {
        #pragma unroll
        for (int qq = 0; qq < 3; ++qq) {
            const float4 oa = *(const float4*)&red_acc[qq][lane][0];
            acc[0] += oa.x; acc[1] += oa.y; acc[2] += oa.z; acc[3] += oa.w;
            den += red_den[qq][lane];
        }
        den += __shfl_xor(den, 16);
        den += __shfl_xor(den, 32);           // full-row den at matching r16
        #pragma unroll
        for (int q = 0; q < 4; ++q) {
            const int orow = g * 4 + q;       // C row for this lane
            const float dq = __shfl(den, orow);
            float rv = acc[q] / dq;
            rv = fmaxf(rv, 0.f);
            out[((size_t)(b * NV) + i0 + orow) * OUTD + h * 16 + r16] = rv;
        }
    }
}

extern "C" void kernel_launch(void* const* d_in, const int* in_sizes, int n_in,
                              void* d_out, int out_size, void* d_ws, size_t ws_size,
                              hipStream_t stream)
{
    const float* x   = (const float*)d_in[0];
    const float* adj = (const float*)d_in[1];
    const float* W   = (const float*)d_in[2];
    const float* a   = (const float*)d_in[3];
    float* out = (float*)d_out;

    char* ws = (char*)d_ws;
    ushort* xhi    = (ushort*)ws;                                  // 1 MB
    float* dst_t   = (float*)(ws + 1024 * 1024);                   // 128 KB
    float* src     = (float*)(ws + 1024 * 1024 + 128 * 1024);      // 128 KB
    uint32_t* bits = (uint32_t*)(ws + 1024 * 1024 + 256 * 1024);   // 512 KB

    kA<<<512 + BV * NV, 256, 0, stream>>>(x, adj, W, a, bits, xhi, src, dst_t);
    kB<<<2048, 256, 0, stream>>>(bits, xhi, dst_t, src, out);
}

// Round 8
// 30.886 us; speedup vs baseline: 1.3641x; 1.2254x over previous
//
#include <hip/hip_runtime.h>
#include <hip/hip_bf16.h>
#include <math.h>
#include <stdint.h>

#define BV 4
#define NV 1024
#define IND 128
#define OUTD 128
#define NH 8
#define DD 16

typedef __attribute__((ext_vector_type(8))) short bf16x8;
typedef __attribute__((ext_vector_type(4))) float f32x4;

__device__ __forceinline__ ushort bf16rne(float f) {
    uint32_t u = __float_as_uint(f);
    u += 0x7fff + ((u >> 16) & 1);
    return (ushort)(u >> 16);
}

// pack two f32 -> two bf16 in one VALU inst (T12 recipe; no builtin on gfx950)
__device__ __forceinline__ uint32_t cvtpk_bf16(float lo, float hi) {
    uint32_t r;
    asm("v_cvt_pk_bf16_f32 %0, %1, %2" : "=v"(r) : "v"(lo), "v"(hi));
    return r;
}

// ---- kernel A: block-specialized {projection+transpose+dots | mask bits} ----
__global__ __launch_bounds__(256) void kA(
    const float* __restrict__ x, const float* __restrict__ adj,
    const float* __restrict__ W, const float* __restrict__ a,
    uint32_t* __restrict__ bits, ushort* __restrict__ xhi,
    float* __restrict__ src, float* __restrict__ dst_t)
{
    const int pid = blockIdx.x;
    const int tid = threadIdx.x;

    if (pid >= 512) {
        // ---------------- mask bitwords (diagonal forced in) ----------------
        const int row = pid - 512;           // b*NV + i
        const int i = row & (NV - 1);
        const int wave = tid >> 6, lane = tid & 63;
        const float* arow = adj + (size_t)row * NV;
        #pragma unroll
        for (int r = 0; r < 4; ++r) {
            const int j = (r * 4 + wave) * 64 + lane;
            const bool m = (arow[j] > 0.f) || (j == i);
            const unsigned long long bal = __ballot(m);
            if (lane == 0) {
                bits[(size_t)row * 32 + (r * 4 + wave) * 2]     = (uint32_t)bal;
                bits[(size_t)row * 32 + (r * 4 + wave) * 2 + 1] = (uint32_t)(bal >> 32);
            }
        }
        return;
    }

    // ------------- projection: 64-row x 16-d tile per block ------------------
    const int jt = pid & 15, bh = pid >> 4;  // bh = b*8+h
    const int b = bh >> 3, h = bh & 7;
    const int j0 = jt * 64;
    const int jl = tid >> 2, dq = tid & 3;   // 4 threads per row, 4 d each
    const int gj = b * NV + j0 + jl;

    float acc0 = 0.f, acc1 = 0.f, acc2 = 0.f, acc3 = 0.f;
    const float* xrow = x + (size_t)gj * IND;
    const float* wcol = W + h * DD + dq * 4;

    #pragma unroll
    for (int kc = 0; kc < IND; kc += 32) {
        float4 xr[8];
        #pragma unroll
        for (int u = 0; u < 8; ++u)
            xr[u] = *(const float4*)&xrow[kc + u * 4];
        #pragma unroll
        for (int u = 0; u < 8; ++u) {
            #pragma unroll
            for (int v = 0; v < 4; ++v) {
                const float xs = ((const float*)&xr[u])[v];
                const float4 w = *(const float4*)&wcol[(size_t)(kc + u * 4 + v) * OUTD];
                acc0 = fmaf(xs, w.x, acc0);
                acc1 = fmaf(xs, w.y, acc1);
                acc2 = fmaf(xs, w.z, acc2);
                acc3 = fmaf(xs, w.w, acc3);
            }
        }
    }

    // src/dst per-head dots (4-lane partial -> combine), raw (no pre-scale)
    {
        const int d0 = dq * 4;
        float s = acc0 * a[d0] + acc1 * a[d0 + 1] + acc2 * a[d0 + 2] + acc3 * a[d0 + 3];
        float t = acc0 * a[DD + d0] + acc1 * a[DD + d0 + 1] + acc2 * a[DD + d0 + 2] + acc3 * a[DD + d0 + 3];
        s += __shfl_xor(s, 1); s += __shfl_xor(s, 2);
        t += __shfl_xor(t, 1); t += __shfl_xor(t, 2);
        if (dq == 0) {
            src[(size_t)gj * NH + h] = s;
            dst_t[(size_t)bh * NV + j0 + jl] = t;
        }
    }

    // bf16 round, transpose to [d][j] via small LDS tile
    __shared__ ushort thi[16][80];
    {
        const float av[4] = {acc0, acc1, acc2, acc3};
        #pragma unroll
        for (int i2 = 0; i2 < 4; ++i2)
            thi[dq * 4 + i2][jl] = bf16rne(av[i2]);
    }
    __syncthreads();
    if (tid < 128) {
        const int d = tid >> 3, jo = tid & 7;
        const uint4 vh = *(const uint4*)&thi[d][jo * 8];
        const size_t base = ((size_t)(bh * 16 + d)) * NV + j0 + jo * 8;
        *(uint4*)&xhi[base] = vh;
    }
}

// --- kernel B: 16-row blocks, 4 j-quarter waves, fast exp + hw bf16 pack ----
__global__ __launch_bounds__(256, 6) void kB(
    const uint32_t* __restrict__ bits, const ushort* __restrict__ xhi,
    const float* __restrict__ dst_t, const float* __restrict__ src,
    float* __restrict__ out)
{
    // grid 2048; XCD-swizzle: blocks on one XCD share 4 bh slabs
    const int bid = blockIdx.x;
    const int xcd = bid & 7, t2 = (bid >> 3) & 3, it = bid >> 5;
    const int bh = xcd * 4 + t2;             // 0..31
    const int b = bh >> 3, h = bh & 7;
    const int i0 = it * 16;

    const int tid = threadIdx.x;
    const int jq = tid >> 6, lane = tid & 63;  // wave = j-quarter
    const int g = lane >> 4, r16 = lane & 15;

    __shared__ float dstl[NV];               // 4 KB
    __shared__ float mxr[4][16];
    __shared__ float red_acc[3][64][4];      // 3 KB
    __shared__ float red_den[3][64];

    // ---- stage dstl + per-lane globals ----
    {
        const float4* gd = (const float4*)(dst_t + (size_t)bh * NV);
        *(float4*)&dstl[tid * 4] = gd[tid];
    }
    const int grow = b * NV + i0 + r16;      // this lane's i-row
    const float srcv = src[(size_t)grow * NH + h];
    uint32_t blw[8];
    #pragma unroll
    for (int s = 0; s < 8; ++s)
        blw[s] = bits[(size_t)grow * 32 + jq * 8 + s];
    __syncthreads();

    // ---- prepass: masked max of dst over this wave's j-quarter ----
    float dmax = -INFINITY;
    #pragma unroll
    for (int s = 0; s < 8; ++s) {
        const int base = jq * 256 + s * 32 + g * 8;
        const uint32_t bb = (blw[s] >> (g * 8)) & 0xffu;
        const float4 v0 = *(const float4*)&dstl[base];
        const float4 v1 = *(const float4*)&dstl[base + 4];
        const float dv[8] = {v0.x, v0.y, v0.z, v0.w, v1.x, v1.y, v1.z, v1.w};
        #pragma unroll
        for (int t = 0; t < 8; ++t) {
            const float sel = (bb & (1u << t)) ? dv[t] : -INFINITY;
            dmax = fmaxf(dmax, sel);
        }
    }
    dmax = fmaxf(dmax, __shfl_xor(dmax, 16));
    dmax = fmaxf(dmax, __shfl_xor(dmax, 32));
    if (g == 0) mxr[jq][r16] = dmax;
    __syncthreads();
    dmax = fmaxf(fmaxf(mxr[0][r16], mxr[1][r16]), fmaxf(mxr[2][r16], mxr[3][r16]));
    const float S = srcv + dmax;
    const float mxv = fmaxf(S, 0.2f * S);    // same op chain as per-element

    // ---- main loop: 8 iters over this wave's j-quarter ----
    f32x4 acc = {0.f, 0.f, 0.f, 0.f};
    float den0 = 0.f, den1 = 0.f;
    const ushort* xrow = xhi + ((size_t)(bh * 16 + r16)) * NV;
    #pragma unroll
    for (int s = 0; s < 8; ++s) {
        const int base = jq * 256 + s * 32 + g * 8;
        const uint32_t bb = (blw[s] >> (g * 8)) & 0xffu;
        const float4 v0 = *(const float4*)&dstl[base];
        const float4 v1 = *(const float4*)&dstl[base + 4];
        const float dv[8] = {v0.x, v0.y, v0.z, v0.w, v1.x, v1.y, v1.z, v1.w};
        union { uint32_t u[4]; bf16x8 v; } af;
        #pragma unroll
        for (int p = 0; p < 4; ++p) {
            float e0 = srcv + dv[2 * p];
            float e1 = srcv + dv[2 * p + 1];
            e0 = fmaxf(e0, 0.2f * e0);
            e1 = fmaxf(e1, 0.2f * e1);
            const float x0 = __expf(e0 - mxv);   // native v_mul+v_exp
            const float x1 = __expf(e1 - mxv);
            const float w0 = (bb & (1u << (2 * p))) ? x0 : 1.0f;
            const float w1 = (bb & (1u << (2 * p + 1))) ? x1 : 1.0f;
            den0 += w0;
            den1 += w1;
            af.u[p] = cvtpk_bf16(w0, w1);        // 1 VALU inst per pair
        }
        const bf16x8 vh = *(const bf16x8*)&xrow[base];   // B-frag from L1/L2
        acc = __builtin_amdgcn_mfma_f32_16x16x32_bf16(af.v, vh, acc, 0, 0, 0);
    }
    float den = den0 + den1;

    // ---- epilogue: cross-quarter reduce + normalize + relu + store ----
    if (jq > 0) {
        *(float4*)&red_acc[jq - 1][lane][0] = *(float4*)&acc;
        red_den[jq - 1][lane] = den;
    }
    __syncthreads();
    if (jq == 0) {
        #pragma unroll
        for (int qq = 0; qq < 3; ++qq) {
            const float4 oa = *(const float4*)&red_acc[qq][lane][0];
            acc[0] += oa.x; acc[1] += oa.y; acc[2] += oa.z; acc[3] += oa.w;
            den += red_den[qq][lane];
        }
        den += __shfl_xor(den, 16);
        den += __shfl_xor(den, 32);           // full-row den at matching r16
        #pragma unroll
        for (int q = 0; q < 4; ++q) {
            const int orow = g * 4 + q;       // C row for this lane
            const float dq = __shfl(den, orow);
            float rv = acc[q] / dq;
            rv = fmaxf(rv, 0.f);
            out[((size_t)(b * NV) + i0 + orow) * OUTD + h * 16 + r16] = rv;
        }
    }
}

extern "C" void kernel_launch(void* const* d_in, const int* in_sizes, int n_in,
                              void* d_out, int out_size, void* d_ws, size_t ws_size,
                              hipStream_t stream)
{
    const float* x   = (const float*)d_in[0];
    const float* adj = (const float*)d_in[1];
    const float* W   = (const float*)d_in[2];
    const float* a   = (const float*)d_in[3];
    float* out = (float*)d_out;

    char* ws = (char*)d_ws;
    ushort* xhi    = (ushort*)ws;                                  // 1 MB
    float* dst_t   = (float*)(ws + 1024 * 1024);                   // 128 KB
    float* src     = (float*)(ws + 1024 * 1024 + 128 * 1024);      // 128 KB
    uint32_t* bits = (uint32_t*)(ws + 1024 * 1024 + 256 * 1024);   // 512 KB

    kA<<<512 + BV * NV, 256, 0, stream>>>(x, adj, W, a, bits, xhi, src, dst_t);
    kB<<<2048, 256, 0, stream>>>(bits, xhi, dst_t, src, out);
}